// Round 2
// baseline (431.899 us; speedup 1.0000x reference)
//
#include <hip/hip_runtime.h>
#include <math.h>

#define N_NODES 20000
#define N_EDGES 320000
#define NFEAT 512
#define NHID 256
#define NCLASS 64

__device__ __forceinline__ float selu_f(float x) {
    const float alpha = 1.6732632423543772f;
    const float scale = 1.0507009873554805f;
    return x > 0.f ? scale * x : scale * alpha * (expf(x) - 1.f);
}

// ---------- CSR build ----------
__global__ void k_count(const int* __restrict__ row, int* __restrict__ counts) {
    int e = blockIdx.x * blockDim.x + threadIdx.x;
    if (e < N_EDGES) atomicAdd(&counts[row[e]], 1);
}

__global__ void k_scan(const int* __restrict__ counts, int* __restrict__ row_ptr,
                       int* __restrict__ write_ptr) {
    __shared__ int s[1024];
    int tid = threadIdx.x;
    int offset = 0;
    for (int base = 0; base < N_NODES; base += 1024) {
        int i = base + tid;
        int v = (i < N_NODES) ? counts[i] : 0;
        s[tid] = v;
        __syncthreads();
        for (int d = 1; d < 1024; d <<= 1) {
            int t = (tid >= d) ? s[tid - d] : 0;
            __syncthreads();
            s[tid] += t;
            __syncthreads();
        }
        int incl = s[tid];
        if (i < N_NODES) {
            int ex = offset + incl - v;
            row_ptr[i] = ex;
            write_ptr[i] = ex;
        }
        int tot = s[1023];
        __syncthreads();
        offset += tot;
    }
    if (tid == 0) row_ptr[N_NODES] = offset;
}

__global__ void k_scatter(const int* __restrict__ row, const int* __restrict__ col,
                          const float* __restrict__ w, int* __restrict__ write_ptr,
                          int* __restrict__ scol, float* __restrict__ sw) {
    int e = blockIdx.x * blockDim.x + threadIdx.x;
    if (e < N_EDGES) {
        int r = row[e];
        int pos = atomicAdd(&write_ptr[r], 1);
        scol[pos] = col[e];
        sw[pos] = w[e];
    }
}

// ---------- fp32 tiled GEMM: C[M,N] = A[M,K] @ B[K,N], 64x64 tile ----------
__global__ __launch_bounds__(256) void k_gemm(const float* __restrict__ A,
                                              const float* __restrict__ B,
                                              float* __restrict__ C, int M, int N, int K) {
    __shared__ float As[16][65];   // +1 pad: avoid 16-way bank conflict on store
    __shared__ float Bs[16][64];
    int tid = threadIdx.x;
    int tx = tid & 15, ty = tid >> 4;
    int m0 = blockIdx.x * 64, n0 = blockIdx.y * 64;
    float acc[4][4] = {};
    for (int kt = 0; kt < K; kt += 16) {
        #pragma unroll
        for (int l = 0; l < 4; ++l) {
            int idx = tid + l * 256;
            int r = idx >> 4, kk = idx & 15;
            int gr = m0 + r;
            As[kk][r] = (gr < M) ? A[(size_t)gr * K + kt + kk] : 0.f;
        }
        #pragma unroll
        for (int l = 0; l < 4; ++l) {
            int idx = tid + l * 256;
            int c = idx & 63, kk = idx >> 6;
            Bs[kk][c] = B[(size_t)(kt + kk) * N + n0 + c];
        }
        __syncthreads();
        #pragma unroll
        for (int k = 0; k < 16; ++k) {
            float a[4], b[4];
            #pragma unroll
            for (int i = 0; i < 4; ++i) a[i] = As[k][ty * 4 + i];
            #pragma unroll
            for (int j = 0; j < 4; ++j) b[j] = Bs[k][tx * 4 + j];
            #pragma unroll
            for (int i = 0; i < 4; ++i)
                #pragma unroll
                for (int j = 0; j < 4; ++j)
                    acc[i][j] = fmaf(a[i], b[j], acc[i][j]);
        }
        __syncthreads();
    }
    #pragma unroll
    for (int i = 0; i < 4; ++i) {
        int gr = m0 + ty * 4 + i;
        if (gr < M) {
            #pragma unroll
            for (int j = 0; j < 4; ++j)
                C[(size_t)gr * N + n0 + tx * 4 + j] = acc[i][j];
        }
    }
}

// ---------- layer-1 aggregation: h1 = selu(CSR-gather(support1) + b1), 1 wave/node ----------
__global__ __launch_bounds__(256) void k_agg1(const float* __restrict__ support,
                                              const int* __restrict__ row_ptr,
                                              const int* __restrict__ scol,
                                              const float* __restrict__ sw,
                                              const float* __restrict__ b1,
                                              float* __restrict__ h1) {
    int wave = threadIdx.x >> 6, lane = threadIdx.x & 63;
    int node = blockIdx.x * 4 + wave;
    if (node >= N_NODES) return;
    int e0 = row_ptr[node], e1 = row_ptr[node + 1];
    float acc[4] = {0.f, 0.f, 0.f, 0.f};
    for (int e = e0; e < e1; ++e) {
        int c = scol[e];
        float w = sw[e];
        const float* sp = support + (size_t)c * NHID + lane;
        #pragma unroll
        for (int j = 0; j < 4; ++j) acc[j] = fmaf(w, sp[j * 64], acc[j]);
    }
    #pragma unroll
    for (int j = 0; j < 4; ++j)
        h1[(size_t)node * NHID + j * 64 + lane] = selu_f(acc[j] + b1[j * 64 + lane]);
}

// ---------- layer-2 aggregation fused with mean accumulation (h2 never stored) ----------
__global__ __launch_bounds__(256) void k_agg2(const float* __restrict__ support2,
                                              const int* __restrict__ row_ptr,
                                              const int* __restrict__ scol,
                                              const float* __restrict__ sw,
                                              const float* __restrict__ b2,
                                              float* __restrict__ gsum) {
    __shared__ float bsum[64];
    int tid = threadIdx.x;
    if (tid < 64) bsum[tid] = 0.f;
    __syncthreads();
    int wave = tid >> 6, lane = tid & 63;
    int node = blockIdx.x * 4 + wave;
    if (node < N_NODES) {
        int e0 = row_ptr[node], e1 = row_ptr[node + 1];
        float acc = 0.f;
        for (int e = e0; e < e1; ++e)
            acc = fmaf(sw[e], support2[(size_t)scol[e] * NCLASS + lane], acc);
        float v = selu_f(acc + b2[lane]);
        atomicAdd(&bsum[lane], v);
    }
    __syncthreads();
    if (tid < 64) atomicAdd(&gsum[tid], bsum[tid]);
}

// ---------- mean -> selu -> log_softmax, single wave ----------
__global__ void k_final(const float* __restrict__ gsum, float* __restrict__ out) {
    int lane = threadIdx.x;  // 64 threads = 1 wave
    float v = gsum[lane] * (1.0f / N_NODES);
    v = selu_f(v);
    float m = v;
    #pragma unroll
    for (int off = 32; off >= 1; off >>= 1) m = fmaxf(m, __shfl_xor(m, off));
    float ex = expf(v - m);
    float s = ex;
    #pragma unroll
    for (int off = 32; off >= 1; off >>= 1) s += __shfl_xor(s, off);
    out[lane] = v - m - logf(s);
}

extern "C" void kernel_launch(void* const* d_in, const int* in_sizes, int n_in,
                              void* d_out, int out_size, void* d_ws, size_t ws_size,
                              hipStream_t stream) {
    const float* x  = (const float*)d_in[0];
    const int* ei   = (const int*)d_in[1];     // [2, E]: rows then cols
    const float* ew = (const float*)d_in[2];
    const float* W1 = (const float*)d_in[3];
    const float* b1 = (const float*)d_in[4];
    const float* W2 = (const float*)d_in[5];
    const float* b2 = (const float*)d_in[6];
    float* out = (float*)d_out;
    const int* e_row = ei;
    const int* e_col = ei + N_EDGES;

    char* p = (char*)d_ws;
    float* support1 = (float*)p;  p += (size_t)N_NODES * NHID * 4;     // 20.48 MB
    float* h1       = (float*)p;  p += (size_t)N_NODES * NHID * 4;     // 20.48 MB
    int* counts     = (int*)p;    p += (size_t)N_NODES * 4;
    int* row_ptr    = (int*)p;    p += (size_t)(N_NODES + 1) * 4;
    int* write_ptr  = (int*)p;    p += (size_t)N_NODES * 4;
    int* scol       = (int*)p;    p += (size_t)N_EDGES * 4;
    float* sw       = (float*)p;  p += (size_t)N_EDGES * 4;
    float* gsum     = (float*)p;  p += 64 * 4;
    // support2 aliases support1's region: support1 is dead after k_agg1,
    // and k_gemm(h1,W2)->support2 runs after. Saves 5.1 MB of ws.
    float* support2 = support1;

    hipMemsetAsync(counts, 0, (size_t)N_NODES * 4, stream);
    hipMemsetAsync(gsum, 0, 64 * 4, stream);

    k_count<<<(N_EDGES + 255) / 256, 256, 0, stream>>>(e_row, counts);
    k_scan<<<1, 1024, 0, stream>>>(counts, row_ptr, write_ptr);
    k_scatter<<<(N_EDGES + 255) / 256, 256, 0, stream>>>(e_row, e_col, ew, write_ptr, scol, sw);

    k_gemm<<<dim3((N_NODES + 63) / 64, NHID / 64), 256, 0, stream>>>(x, W1, support1,
                                                                     N_NODES, NHID, NFEAT);
    k_agg1<<<N_NODES / 4, 256, 0, stream>>>(support1, row_ptr, scol, sw, b1, h1);
    k_gemm<<<dim3((N_NODES + 63) / 64, NCLASS / 64), 256, 0, stream>>>(h1, W2, support2,
                                                                       N_NODES, NCLASS, NHID);
    k_agg2<<<N_NODES / 4, 256, 0, stream>>>(support2, row_ptr, scol, sw, b2, gsum);
    k_final<<<1, 64, 0, stream>>>(gsum, out);
}

// Round 3
// 295.868 us; speedup vs baseline: 1.4598x; 1.4598x over previous
//
#include <hip/hip_runtime.h>
#include <math.h>

#define N_NODES 20000
#define N_EDGES 320000
#define NFEAT 512
#define NHID 256
#define NCLASS 64

typedef __attribute__((ext_vector_type(8))) short bf16x8;
typedef __attribute__((ext_vector_type(4))) float f32x4;

__device__ __forceinline__ float selu_f(float x) {
    const float alpha = 1.6732632423543772f;
    const float scale = 1.0507009873554805f;
    return x > 0.f ? scale * x : scale * alpha * (expf(x) - 1.f);
}

__device__ __forceinline__ short f2bf(float f) {
    unsigned u = __builtin_bit_cast(unsigned, f);
    unsigned r = (u + 0x7FFFu + ((u >> 16) & 1u)) >> 16;   // RNE
    return (short)r;
}

__device__ __forceinline__ float bf2f(unsigned short b) {
    unsigned u = ((unsigned)b) << 16;
    return __builtin_bit_cast(float, u);
}

// ---------- casts ----------
__global__ void k_cast_x(const float* __restrict__ in, short* __restrict__ out, int n8) {
    int i = blockIdx.x * blockDim.x + threadIdx.x;
    if (i >= n8) return;
    const float4* p = (const float4*)(in + (size_t)i * 8);
    float4 a = p[0], b = p[1];
    bf16x8 o;
    o[0] = f2bf(a.x); o[1] = f2bf(a.y); o[2] = f2bf(a.z); o[3] = f2bf(a.w);
    o[4] = f2bf(b.x); o[5] = f2bf(b.y); o[6] = f2bf(b.z); o[7] = f2bf(b.w);
    *(bf16x8*)(out + (size_t)i * 8) = o;
}

// W[K,N] fp32 -> Wt[N,K] bf16
__global__ void k_cast_t(const float* __restrict__ in, short* __restrict__ out, int K, int N) {
    int t = blockIdx.x * blockDim.x + threadIdx.x;
    if (t >= K * N) return;
    int n = t / K, k = t % K;
    out[t] = f2bf(in[(size_t)k * N + n]);
}

// ---------- CSR build ----------
__global__ void k_count(const int* __restrict__ row, int* __restrict__ counts) {
    int e = blockIdx.x * blockDim.x + threadIdx.x;
    if (e < N_EDGES) atomicAdd(&counts[row[e]], 1);
}

__global__ void k_scan(const int* __restrict__ counts, int* __restrict__ row_ptr,
                       int* __restrict__ write_ptr) {
    __shared__ int wsum[16];
    __shared__ int carry;
    int tid = threadIdx.x;            // 1024 threads = 16 waves
    int wave = tid >> 6, lane = tid & 63;
    if (tid == 0) carry = 0;
    __syncthreads();
    for (int base = 0; base < N_NODES; base += 1024) {
        int i = base + tid;
        int v = (i < N_NODES) ? counts[i] : 0;
        int s = v;
        #pragma unroll
        for (int d = 1; d < 64; d <<= 1) {
            int t = __shfl_up(s, d);
            if (lane >= d) s += t;
        }
        if (lane == 63) wsum[wave] = s;
        __syncthreads();
        if (wave == 0) {
            int t = (lane < 16) ? wsum[lane] : 0;
            #pragma unroll
            for (int d = 1; d < 16; d <<= 1) {
                int u = __shfl_up(t, d);
                if (lane >= d) t += u;
            }
            if (lane < 16) wsum[lane] = t;     // inclusive over waves
        }
        __syncthreads();
        int woff = (wave == 0) ? 0 : wsum[wave - 1];
        int excl = carry + woff + s - v;
        if (i < N_NODES) { row_ptr[i] = excl; write_ptr[i] = excl; }
        int total = wsum[15];
        __syncthreads();
        if (tid == 0) carry += total;
        __syncthreads();
    }
    if (tid == 0) row_ptr[N_NODES] = carry;
}

__global__ void k_scatter(const int* __restrict__ row, const int* __restrict__ col,
                          const float* __restrict__ w, int* __restrict__ write_ptr,
                          int* __restrict__ scol, float* __restrict__ sw) {
    int e = blockIdx.x * blockDim.x + threadIdx.x;
    if (e < N_EDGES) {
        int r = row[e];
        int pos = atomicAdd(&write_ptr[r], 1);
        scol[pos] = col[e];
        sw[pos] = w[e];
    }
}

// ---------- bf16 MFMA GEMM: C[M,N] = A[M,K] @ Bt[N,K]^T, C emitted as bf16 ----------
// 4 waves in 2x2; each wave owns (BM/2)x(BN/2) = MREP*16 x NREP*16.
template<int BM, int BN, int MREP, int NREP>
__global__ __launch_bounds__(256) void k_gemm_bf16(
    const short* __restrict__ A, const short* __restrict__ Bt,
    short* __restrict__ C, int M, int N, int K)
{
    constexpr int BK = 32;
    constexpr int LDT = BK + 8;     // +16B pad: frag-read conflicts 8-way -> 2-way (free, m136)
    __shared__ short As[BM * LDT];
    __shared__ short Bs[BN * LDT];
    const int tid = threadIdx.x;
    const int lane = tid & 63;
    const int w = tid >> 6;
    const int wr = w >> 1, wc = w & 1;
    const int m0 = blockIdx.x * BM, n0 = blockIdx.y * BN;

    f32x4 acc[MREP][NREP] = {};

    constexpr int A_ITER = BM * BK / 8 / 256;
    constexpr int B_ITER = BN * BK / 8 / 256;

    for (int kt = 0; kt < K; kt += BK) {
        #pragma unroll
        for (int it = 0; it < A_ITER; ++it) {
            int idx = tid + it * 256;
            int r = idx >> 2, seg = idx & 3;       // 4 x 8-elem segs per row
            int gr = m0 + r; if (gr >= M) gr = M - 1;   // clamp: dup load, store predicated
            bf16x8 v = *(const bf16x8*)(A + (size_t)gr * K + kt + seg * 8);
            *(bf16x8*)(As + r * LDT + seg * 8) = v;
        }
        #pragma unroll
        for (int it = 0; it < B_ITER; ++it) {
            int idx = tid + it * 256;
            int r = idx >> 2, seg = idx & 3;
            bf16x8 v = *(const bf16x8*)(Bt + (size_t)(n0 + r) * K + kt + seg * 8);
            *(bf16x8*)(Bs + r * LDT + seg * 8) = v;
        }
        __syncthreads();
        bf16x8 a[MREP], b[NREP];
        #pragma unroll
        for (int m = 0; m < MREP; ++m)
            a[m] = *(const bf16x8*)(As + (wr * (BM / 2) + m * 16 + (lane & 15)) * LDT + (lane >> 4) * 8);
        #pragma unroll
        for (int n = 0; n < NREP; ++n)
            b[n] = *(const bf16x8*)(Bs + (wc * (BN / 2) + n * 16 + (lane & 15)) * LDT + (lane >> 4) * 8);
        #pragma unroll
        for (int m = 0; m < MREP; ++m)
            #pragma unroll
            for (int n = 0; n < NREP; ++n)
                acc[m][n] = __builtin_amdgcn_mfma_f32_16x16x32_bf16(a[m], b[n], acc[m][n], 0, 0, 0);
        __syncthreads();
    }
    // C/D layout (m89): col = lane&15, row = (lane>>4)*4 + reg
    #pragma unroll
    for (int m = 0; m < MREP; ++m) {
        #pragma unroll
        for (int n = 0; n < NREP; ++n) {
            #pragma unroll
            for (int r = 0; r < 4; ++r) {
                int grow = m0 + wr * (BM / 2) + m * 16 + (lane >> 4) * 4 + r;
                int gcol = n0 + wc * (BN / 2) + n * 16 + (lane & 15);
                if (grow < M) C[(size_t)grow * N + gcol] = f2bf(acc[m][n][r]);
            }
        }
    }
}

// ---------- layer-1 aggregation: h1 = selu(gather(support1) + b1), 1 wave/node ----------
__global__ __launch_bounds__(256) void k_agg1(const short* __restrict__ support,
                                              const int* __restrict__ row_ptr,
                                              const int* __restrict__ scol,
                                              const float* __restrict__ sw,
                                              const float* __restrict__ b1,
                                              short* __restrict__ h1) {
    int wave = threadIdx.x >> 6, lane = threadIdx.x & 63;
    int node = blockIdx.x * 4 + wave;
    if (node >= N_NODES) return;
    int e0 = row_ptr[node], e1 = row_ptr[node + 1];
    float acc[4] = {0.f, 0.f, 0.f, 0.f};
    for (int e = e0; e < e1; ++e) {
        int c = scol[e];
        float wgt = sw[e];
        ushort4 v = *(const ushort4*)(support + (size_t)c * NHID + lane * 4);  // 512B/row coalesced
        acc[0] = fmaf(wgt, bf2f(v.x), acc[0]);
        acc[1] = fmaf(wgt, bf2f(v.y), acc[1]);
        acc[2] = fmaf(wgt, bf2f(v.z), acc[2]);
        acc[3] = fmaf(wgt, bf2f(v.w), acc[3]);
    }
    ushort4 o;
    o.x = (unsigned short)f2bf(selu_f(acc[0] + b1[lane * 4 + 0]));
    o.y = (unsigned short)f2bf(selu_f(acc[1] + b1[lane * 4 + 1]));
    o.z = (unsigned short)f2bf(selu_f(acc[2] + b1[lane * 4 + 2]));
    o.w = (unsigned short)f2bf(selu_f(acc[3] + b1[lane * 4 + 3]));
    *(ushort4*)(h1 + (size_t)node * NHID + lane * 4) = o;
}

// ---------- layer-2 aggregation fused with mean accumulation; 8 nodes/wave ----------
__global__ __launch_bounds__(256) void k_agg2(const short* __restrict__ support2,
                                              const int* __restrict__ row_ptr,
                                              const int* __restrict__ scol,
                                              const float* __restrict__ sw,
                                              const float* __restrict__ b2,
                                              float* __restrict__ gsum) {
    __shared__ float bsum[64];
    int tid = threadIdx.x;
    if (tid < 64) bsum[tid] = 0.f;
    __syncthreads();
    int wave = tid >> 6, lane = tid & 63;
    float local = 0.f;
    for (int q = 0; q < 8; ++q) {
        int node = blockIdx.x * 32 + wave * 8 + q;
        if (node >= N_NODES) break;
        int e0 = row_ptr[node], e1 = row_ptr[node + 1];
        float acc = 0.f;
        for (int e = e0; e < e1; ++e)
            acc = fmaf(sw[e], bf2f((unsigned short)support2[(size_t)scol[e] * NCLASS + lane]), acc);
        local += selu_f(acc + b2[lane]);
    }
    atomicAdd(&bsum[lane], local);
    __syncthreads();
    if (tid < 64) atomicAdd(&gsum[tid], bsum[tid]);
}

// ---------- mean -> selu -> log_softmax, single wave ----------
__global__ void k_final(const float* __restrict__ gsum, float* __restrict__ out) {
    int lane = threadIdx.x;  // 64 threads
    float v = gsum[lane] * (1.0f / N_NODES);
    v = selu_f(v);
    float m = v;
    #pragma unroll
    for (int off = 32; off >= 1; off >>= 1) m = fmaxf(m, __shfl_xor(m, off));
    float ex = expf(v - m);
    float s = ex;
    #pragma unroll
    for (int off = 32; off >= 1; off >>= 1) s += __shfl_xor(s, off);
    out[lane] = v - m - logf(s);
}

extern "C" void kernel_launch(void* const* d_in, const int* in_sizes, int n_in,
                              void* d_out, int out_size, void* d_ws, size_t ws_size,
                              hipStream_t stream) {
    const float* x  = (const float*)d_in[0];
    const int* ei   = (const int*)d_in[1];
    const float* ew = (const float*)d_in[2];
    const float* W1 = (const float*)d_in[3];
    const float* b1 = (const float*)d_in[4];
    const float* W2 = (const float*)d_in[5];
    const float* b2 = (const float*)d_in[6];
    float* out = (float*)d_out;
    const int* e_row = ei;
    const int* e_col = ei + N_EDGES;

    char* p = (char*)d_ws;
    short* xb       = (short*)p;  p += (size_t)N_NODES * NFEAT * 2;    // 20.48 MB
    short* w1t      = (short*)p;  p += (size_t)NHID * NFEAT * 2;       //  0.26 MB
    short* w2t      = (short*)p;  p += (size_t)NCLASS * NHID * 2;      //  0.03 MB
    short* support1 = (short*)p;  p += (size_t)N_NODES * NHID * 2;     // 10.24 MB
    int* counts     = (int*)p;    p += (size_t)N_NODES * 4;
    int* row_ptr    = (int*)p;    p += (size_t)(N_NODES + 1) * 4;
    int* write_ptr  = (int*)p;    p += (size_t)N_NODES * 4;
    int* scol       = (int*)p;    p += (size_t)N_EDGES * 4;
    float* sw       = (float*)p;  p += (size_t)N_EDGES * 4;
    float* gsum     = (float*)p;  p += 64 * 4;
    // aliases (lifetimes disjoint): h1 reuses xb (xb dead after gemm1);
    // support2 reuses support1 (dead after agg1).
    short* h1       = xb;
    short* support2 = support1;

    hipMemsetAsync(counts, 0, (size_t)N_NODES * 4, stream);
    hipMemsetAsync(gsum, 0, 64 * 4, stream);

    // CSR build
    k_count<<<(N_EDGES + 255) / 256, 256, 0, stream>>>(e_row, counts);
    k_scan<<<1, 1024, 0, stream>>>(counts, row_ptr, write_ptr);
    k_scatter<<<(N_EDGES + 255) / 256, 256, 0, stream>>>(e_row, e_col, ew, write_ptr, scol, sw);

    // casts
    k_cast_x<<<(N_NODES * NFEAT / 8 + 255) / 256, 256, 0, stream>>>(x, xb, N_NODES * NFEAT / 8);
    k_cast_t<<<(NFEAT * NHID + 255) / 256, 256, 0, stream>>>(W1, w1t, NFEAT, NHID);
    k_cast_t<<<(NHID * NCLASS + 255) / 256, 256, 0, stream>>>(W2, w2t, NHID, NCLASS);

    // layer 1
    k_gemm_bf16<128, 128, 4, 4><<<dim3((N_NODES + 127) / 128, NHID / 128), 256, 0, stream>>>(
        xb, w1t, support1, N_NODES, NHID, NFEAT);
    k_agg1<<<N_NODES / 4, 256, 0, stream>>>(support1, row_ptr, scol, sw, b1, h1);

    // layer 2
    k_gemm_bf16<64, 64, 2, 2><<<dim3((N_NODES + 63) / 64, NCLASS / 64), 256, 0, stream>>>(
        h1, w2t, support2, N_NODES, NCLASS, NHID);
    k_agg2<<<(N_NODES + 31) / 32, 256, 0, stream>>>(support2, row_ptr, scol, sw, b2, gsum);

    k_final<<<1, 64, 0, stream>>>(gsum, out);
}

// Round 4
// 244.304 us; speedup vs baseline: 1.7679x; 1.2111x over previous
//
#include <hip/hip_runtime.h>
#include <math.h>

#define N_NODES 20000
#define N_EDGES 320000
#define NFEAT 512
#define NHID 256
#define NCLASS 64

typedef __attribute__((ext_vector_type(8))) short bf16x8;
typedef __attribute__((ext_vector_type(4))) float f32x4;

__device__ __forceinline__ float selu_f(float x) {
    const float alpha = 1.6732632423543772f;
    const float scale = 1.0507009873554805f;
    return x > 0.f ? scale * x : scale * alpha * (expf(x) - 1.f);
}

__device__ __forceinline__ short f2bf(float f) {
    unsigned u = __builtin_bit_cast(unsigned, f);
    unsigned r = (u + 0x7FFFu + ((u >> 16) & 1u)) >> 16;   // RNE
    return (short)r;
}

__device__ __forceinline__ float bf2f(unsigned short b) {
    unsigned u = ((unsigned)b) << 16;
    return __builtin_bit_cast(float, u);
}

// ---------- casts ----------
__global__ void k_cast_x(const float* __restrict__ in, short* __restrict__ out, int n8) {
    int i = blockIdx.x * blockDim.x + threadIdx.x;
    if (i >= n8) return;
    const float4* p = (const float4*)(in + (size_t)i * 8);
    float4 a = p[0], b = p[1];
    bf16x8 o;
    o[0] = f2bf(a.x); o[1] = f2bf(a.y); o[2] = f2bf(a.z); o[3] = f2bf(a.w);
    o[4] = f2bf(b.x); o[5] = f2bf(b.y); o[6] = f2bf(b.z); o[7] = f2bf(b.w);
    *(bf16x8*)(out + (size_t)i * 8) = o;
}

// W[K,N] fp32 -> Wt[N,K] bf16
__global__ void k_cast_t(const float* __restrict__ in, short* __restrict__ out, int K, int N) {
    int t = blockIdx.x * blockDim.x + threadIdx.x;
    if (t >= K * N) return;
    int n = t / K, k = t % K;
    out[t] = f2bf(in[(size_t)k * N + n]);
}

// ---------- CSR build ----------
__global__ void k_count(const int* __restrict__ row, int* __restrict__ counts) {
    int e = blockIdx.x * blockDim.x + threadIdx.x;
    if (e < N_EDGES) atomicAdd(&counts[row[e]], 1);
}

__global__ void k_scan(const int* __restrict__ counts, int* __restrict__ row_ptr,
                       int* __restrict__ write_ptr) {
    __shared__ int wsum[16];
    __shared__ int carry;
    int tid = threadIdx.x;            // 1024 threads = 16 waves
    int wave = tid >> 6, lane = tid & 63;
    if (tid == 0) carry = 0;
    __syncthreads();
    for (int base = 0; base < N_NODES; base += 1024) {
        int i = base + tid;
        int v = (i < N_NODES) ? counts[i] : 0;
        int s = v;
        #pragma unroll
        for (int d = 1; d < 64; d <<= 1) {
            int t = __shfl_up(s, d);
            if (lane >= d) s += t;
        }
        if (lane == 63) wsum[wave] = s;
        __syncthreads();
        if (wave == 0) {
            int t = (lane < 16) ? wsum[lane] : 0;
            #pragma unroll
            for (int d = 1; d < 16; d <<= 1) {
                int u = __shfl_up(t, d);
                if (lane >= d) t += u;
            }
            if (lane < 16) wsum[lane] = t;     // inclusive over waves
        }
        __syncthreads();
        int woff = (wave == 0) ? 0 : wsum[wave - 1];
        int excl = carry + woff + s - v;
        if (i < N_NODES) { row_ptr[i] = excl; write_ptr[i] = excl; }
        int total = wsum[15];
        __syncthreads();
        if (tid == 0) carry += total;
        __syncthreads();
    }
    if (tid == 0) row_ptr[N_NODES] = carry;
}

// pack (col, weight) per edge -> one 8B load on the gather chain
__global__ void k_scatter(const int* __restrict__ row, const int* __restrict__ col,
                          const float* __restrict__ w, int* __restrict__ write_ptr,
                          int2* __restrict__ epack) {
    int e = blockIdx.x * blockDim.x + threadIdx.x;
    if (e < N_EDGES) {
        int r = row[e];
        int pos = atomicAdd(&write_ptr[r], 1);
        epack[pos] = make_int2(col[e], __builtin_bit_cast(int, w[e]));
    }
}

// ---------- bf16 MFMA GEMM: C[M,N] = A[M,K] @ Bt[N,K]^T, C emitted as bf16 ----------
template<int BM, int BN, int MREP, int NREP>
__global__ __launch_bounds__(256) void k_gemm_bf16(
    const short* __restrict__ A, const short* __restrict__ Bt,
    short* __restrict__ C, int M, int N, int K)
{
    constexpr int BK = 32;
    constexpr int LDT = BK + 8;
    __shared__ short As[BM * LDT];
    __shared__ short Bs[BN * LDT];
    const int tid = threadIdx.x;
    const int lane = tid & 63;
    const int w = tid >> 6;
    const int wr = w >> 1, wc = w & 1;
    const int m0 = blockIdx.x * BM, n0 = blockIdx.y * BN;

    f32x4 acc[MREP][NREP] = {};

    constexpr int A_ITER = BM * BK / 8 / 256;
    constexpr int B_ITER = BN * BK / 8 / 256;

    for (int kt = 0; kt < K; kt += BK) {
        #pragma unroll
        for (int it = 0; it < A_ITER; ++it) {
            int idx = tid + it * 256;
            int r = idx >> 2, seg = idx & 3;
            int gr = m0 + r; if (gr >= M) gr = M - 1;
            bf16x8 v = *(const bf16x8*)(A + (size_t)gr * K + kt + seg * 8);
            *(bf16x8*)(As + r * LDT + seg * 8) = v;
        }
        #pragma unroll
        for (int it = 0; it < B_ITER; ++it) {
            int idx = tid + it * 256;
            int r = idx >> 2, seg = idx & 3;
            bf16x8 v = *(const bf16x8*)(Bt + (size_t)(n0 + r) * K + kt + seg * 8);
            *(bf16x8*)(Bs + r * LDT + seg * 8) = v;
        }
        __syncthreads();
        bf16x8 a[MREP], b[NREP];
        #pragma unroll
        for (int m = 0; m < MREP; ++m)
            a[m] = *(const bf16x8*)(As + (wr * (BM / 2) + m * 16 + (lane & 15)) * LDT + (lane >> 4) * 8);
        #pragma unroll
        for (int n = 0; n < NREP; ++n)
            b[n] = *(const bf16x8*)(Bs + (wc * (BN / 2) + n * 16 + (lane & 15)) * LDT + (lane >> 4) * 8);
        #pragma unroll
        for (int m = 0; m < MREP; ++m)
            #pragma unroll
            for (int n = 0; n < NREP; ++n)
                acc[m][n] = __builtin_amdgcn_mfma_f32_16x16x32_bf16(a[m], b[n], acc[m][n], 0, 0, 0);
        __syncthreads();
    }
    #pragma unroll
    for (int m = 0; m < MREP; ++m) {
        #pragma unroll
        for (int n = 0; n < NREP; ++n) {
            #pragma unroll
            for (int r = 0; r < 4; ++r) {
                int grow = m0 + wr * (BM / 2) + m * 16 + (lane >> 4) * 4 + r;
                int gcol = n0 + wc * (BN / 2) + n * 16 + (lane & 15);
                if (grow < M) C[(size_t)grow * N + gcol] = f2bf(acc[m][n][r]);
            }
        }
    }
}

// ---------- layer-1 aggregation: 1 wave/node, ILP-4 edge unroll ----------
__global__ __launch_bounds__(256) void k_agg1(const short* __restrict__ support,
                                              const int* __restrict__ row_ptr,
                                              const int2* __restrict__ epack,
                                              const float* __restrict__ b1,
                                              short* __restrict__ h1) {
    int wid = (blockIdx.x * 256 + threadIdx.x) >> 6;   // = node
    int lane = threadIdx.x & 63;
    if (wid >= N_NODES) return;
    int e0 = row_ptr[wid], e1 = row_ptr[wid + 1];
    float a0[4] = {}, a1[4] = {}, a2[4] = {}, a3[4] = {};
    int e = e0;
    for (; e + 4 <= e1; e += 4) {
        int2 m0 = epack[e + 0], m1 = epack[e + 1], m2 = epack[e + 2], m3 = epack[e + 3];
        ushort4 v0 = *(const ushort4*)(support + (size_t)m0.x * NHID + lane * 4);
        ushort4 v1 = *(const ushort4*)(support + (size_t)m1.x * NHID + lane * 4);
        ushort4 v2 = *(const ushort4*)(support + (size_t)m2.x * NHID + lane * 4);
        ushort4 v3 = *(const ushort4*)(support + (size_t)m3.x * NHID + lane * 4);
        float w0 = __builtin_bit_cast(float, m0.y), w1 = __builtin_bit_cast(float, m1.y);
        float w2 = __builtin_bit_cast(float, m2.y), w3 = __builtin_bit_cast(float, m3.y);
        a0[0] = fmaf(w0, bf2f(v0.x), a0[0]); a0[1] = fmaf(w0, bf2f(v0.y), a0[1]);
        a0[2] = fmaf(w0, bf2f(v0.z), a0[2]); a0[3] = fmaf(w0, bf2f(v0.w), a0[3]);
        a1[0] = fmaf(w1, bf2f(v1.x), a1[0]); a1[1] = fmaf(w1, bf2f(v1.y), a1[1]);
        a1[2] = fmaf(w1, bf2f(v1.z), a1[2]); a1[3] = fmaf(w1, bf2f(v1.w), a1[3]);
        a2[0] = fmaf(w2, bf2f(v2.x), a2[0]); a2[1] = fmaf(w2, bf2f(v2.y), a2[1]);
        a2[2] = fmaf(w2, bf2f(v2.z), a2[2]); a2[3] = fmaf(w2, bf2f(v2.w), a2[3]);
        a3[0] = fmaf(w3, bf2f(v3.x), a3[0]); a3[1] = fmaf(w3, bf2f(v3.y), a3[1]);
        a3[2] = fmaf(w3, bf2f(v3.z), a3[2]); a3[3] = fmaf(w3, bf2f(v3.w), a3[3]);
    }
    for (; e < e1; ++e) {
        int2 m = epack[e];
        float wgt = __builtin_bit_cast(float, m.y);
        ushort4 v = *(const ushort4*)(support + (size_t)m.x * NHID + lane * 4);
        a0[0] = fmaf(wgt, bf2f(v.x), a0[0]); a0[1] = fmaf(wgt, bf2f(v.y), a0[1]);
        a0[2] = fmaf(wgt, bf2f(v.z), a0[2]); a0[3] = fmaf(wgt, bf2f(v.w), a0[3]);
    }
    ushort4 o;
    o.x = (unsigned short)f2bf(selu_f(a0[0] + a1[0] + a2[0] + a3[0] + b1[lane * 4 + 0]));
    o.y = (unsigned short)f2bf(selu_f(a0[1] + a1[1] + a2[1] + a3[1] + b1[lane * 4 + 1]));
    o.z = (unsigned short)f2bf(selu_f(a0[2] + a1[2] + a2[2] + a3[2] + b1[lane * 4 + 2]));
    o.w = (unsigned short)f2bf(selu_f(a0[3] + a1[3] + a2[3] + a3[3] + b1[lane * 4 + 3]));
    *(ushort4*)(h1 + (size_t)wid * NHID + lane * 4) = o;
}

// ---------- layer-2 aggregation: 1 wave / 2 nodes, ILP-4, atomic-free partials ----------
#define AGG2_NU 2
#define AGG2_WAVES (N_NODES / AGG2_NU)    // 10000
__global__ __launch_bounds__(256) void k_agg2(const short* __restrict__ support2,
                                              const int* __restrict__ row_ptr,
                                              const int2* __restrict__ epack,
                                              const float* __restrict__ b2,
                                              float* __restrict__ partial) {
    int wid = (blockIdx.x * 256 + threadIdx.x) >> 6;
    int lane = threadIdx.x & 63;
    float bias = b2[lane];
    float local = 0.f;
    #pragma unroll
    for (int q = 0; q < AGG2_NU; ++q) {
        int node = wid * AGG2_NU + q;
        int e0 = row_ptr[node], e1 = row_ptr[node + 1];
        float s0 = 0.f, s1 = 0.f, s2 = 0.f, s3 = 0.f;
        int e = e0;
        for (; e + 4 <= e1; e += 4) {
            int2 m0 = epack[e + 0], m1 = epack[e + 1], m2 = epack[e + 2], m3 = epack[e + 3];
            float v0 = bf2f((unsigned short)support2[(size_t)m0.x * NCLASS + lane]);
            float v1 = bf2f((unsigned short)support2[(size_t)m1.x * NCLASS + lane]);
            float v2 = bf2f((unsigned short)support2[(size_t)m2.x * NCLASS + lane]);
            float v3 = bf2f((unsigned short)support2[(size_t)m3.x * NCLASS + lane]);
            s0 = fmaf(__builtin_bit_cast(float, m0.y), v0, s0);
            s1 = fmaf(__builtin_bit_cast(float, m1.y), v1, s1);
            s2 = fmaf(__builtin_bit_cast(float, m2.y), v2, s2);
            s3 = fmaf(__builtin_bit_cast(float, m3.y), v3, s3);
        }
        for (; e < e1; ++e) {
            int2 m = epack[e];
            s0 = fmaf(__builtin_bit_cast(float, m.y),
                      bf2f((unsigned short)support2[(size_t)m.x * NCLASS + lane]), s0);
        }
        local += selu_f(s0 + s1 + s2 + s3 + bias);
    }
    partial[(size_t)wid * NCLASS + lane] = local;
}

// ---------- reduce partials: one block per class ----------
__global__ __launch_bounds__(256) void k_reduce(const float* __restrict__ partial,
                                                float* __restrict__ gsum) {
    int c = blockIdx.x, tid = threadIdx.x;
    float s = 0.f;
    for (int i = tid; i < AGG2_WAVES; i += 256)
        s += partial[(size_t)i * NCLASS + c];
    #pragma unroll
    for (int off = 32; off >= 1; off >>= 1) s += __shfl_xor(s, off);
    __shared__ float red[4];
    if ((tid & 63) == 0) red[tid >> 6] = s;
    __syncthreads();
    if (tid == 0) gsum[c] = red[0] + red[1] + red[2] + red[3];
}

// ---------- mean -> selu -> log_softmax, single wave ----------
__global__ void k_final(const float* __restrict__ gsum, float* __restrict__ out) {
    int lane = threadIdx.x;  // 64 threads
    float v = gsum[lane] * (1.0f / N_NODES);
    v = selu_f(v);
    float m = v;
    #pragma unroll
    for (int off = 32; off >= 1; off >>= 1) m = fmaxf(m, __shfl_xor(m, off));
    float ex = expf(v - m);
    float s = ex;
    #pragma unroll
    for (int off = 32; off >= 1; off >>= 1) s += __shfl_xor(s, off);
    out[lane] = v - m - logf(s);
}

extern "C" void kernel_launch(void* const* d_in, const int* in_sizes, int n_in,
                              void* d_out, int out_size, void* d_ws, size_t ws_size,
                              hipStream_t stream) {
    const float* x  = (const float*)d_in[0];
    const int* ei   = (const int*)d_in[1];
    const float* ew = (const float*)d_in[2];
    const float* W1 = (const float*)d_in[3];
    const float* b1 = (const float*)d_in[4];
    const float* W2 = (const float*)d_in[5];
    const float* b2 = (const float*)d_in[6];
    float* out = (float*)d_out;
    const int* e_row = ei;
    const int* e_col = ei + N_EDGES;

    char* p = (char*)d_ws;
    short* xb       = (short*)p;  p += (size_t)N_NODES * NFEAT * 2;      // 20.48 MB
    short* w1t      = (short*)p;  p += (size_t)NHID * NFEAT * 2;         //  0.26 MB
    short* w2t      = (short*)p;  p += (size_t)NCLASS * NHID * 2;        //  0.03 MB
    short* support1 = (short*)p;  p += (size_t)N_NODES * NHID * 2;       // 10.24 MB
    int* counts     = (int*)p;    p += (size_t)N_NODES * 4;
    int* row_ptr    = (int*)p;    p += (size_t)(N_NODES + 1) * 4;
    int* write_ptr  = (int*)p;    p += (size_t)N_NODES * 4;
    int2* epack     = (int2*)p;   p += (size_t)N_EDGES * 8;              //  2.56 MB
    float* partial  = (float*)p;  p += (size_t)AGG2_WAVES * NCLASS * 4;  //  2.56 MB
    float* gsum     = (float*)p;  p += 64 * 4;
    // aliases (disjoint lifetimes)
    short* h1       = xb;         // xb dead after gemm1
    short* support2 = support1;   // support1 dead after agg1

    hipMemsetAsync(counts, 0, (size_t)N_NODES * 4, stream);

    // CSR build
    k_count<<<(N_EDGES + 255) / 256, 256, 0, stream>>>(e_row, counts);
    k_scan<<<1, 1024, 0, stream>>>(counts, row_ptr, write_ptr);
    k_scatter<<<(N_EDGES + 255) / 256, 256, 0, stream>>>(e_row, e_col, ew, write_ptr, epack);

    // casts
    k_cast_x<<<(N_NODES * NFEAT / 8 + 255) / 256, 256, 0, stream>>>(x, xb, N_NODES * NFEAT / 8);
    k_cast_t<<<(NFEAT * NHID + 255) / 256, 256, 0, stream>>>(W1, w1t, NFEAT, NHID);
    k_cast_t<<<(NHID * NCLASS + 255) / 256, 256, 0, stream>>>(W2, w2t, NHID, NCLASS);

    // layer 1
    k_gemm_bf16<128, 128, 4, 4><<<dim3((N_NODES + 127) / 128, NHID / 128), 256, 0, stream>>>(
        xb, w1t, support1, N_NODES, NHID, NFEAT);
    k_agg1<<<(N_NODES * 64 + 255) / 256, 256, 0, stream>>>(support1, row_ptr, epack, b1, h1);

    // layer 2
    k_gemm_bf16<64, 64, 2, 2><<<dim3((N_NODES + 63) / 64, NCLASS / 64), 256, 0, stream>>>(
        h1, w2t, support2, N_NODES, NCLASS, NHID);
    k_agg2<<<(AGG2_WAVES * 64) / 256, 256, 0, stream>>>(support2, row_ptr, epack, b2, partial);
    k_reduce<<<NCLASS, 256, 0, stream>>>(partial, gsum);

    k_final<<<1, 64, 0, stream>>>(gsum, out);
}